// Round 5
// baseline (779.336 us; speedup 1.0000x reference)
//
#include <hip/hip_runtime.h>

// Problem constants (B=8, N=4096, C=384, heads=8, head_dim=48)
#define B_   8
#define N_   4096
#define C_   384
#define NH_  8
#define HD_  48
#define M_   (B_ * N_)   // 32768 rows

// ---------------- prep kernels ----------------

// W1[k][n]: n<384 -> w_qk transposed (w_qk[n,k]); n>=384 -> w_v transposed.
__global__ __launch_bounds__(256) void prep_w1(const float* __restrict__ w_qk,
                                               const float* __restrict__ w_v,
                                               float* __restrict__ W1)
{
    int idx = blockIdx.x * 256 + threadIdx.x;   // < 384*768
    int k = idx / 768, n = idx % 768;
    W1[idx] = (n < 384) ? w_qk[(size_t)n * 384 + k]
                        : w_v[(size_t)(n - 384) * 384 + k];
}

// W3[k][n] = w_proj[n][k]
__global__ __launch_bounds__(256) void prep_w3(const float* __restrict__ w_proj,
                                               float* __restrict__ W3)
{
    int idx = blockIdx.x * 256 + threadIdx.x;   // < 384*384
    int k = idx / 384, n = idx % 384;
    W3[idx] = w_proj[n * 384 + k];
}

__global__ __launch_bounds__(256) void zerok(float* __restrict__ p, int n)
{
    int i = blockIdx.x * 256 + threadIdx.x;
    if (i < n) p[i] = 0.f;
}

// ---------------- fp32 tiled GEMM ----------------
// C[M,N] = A[M,K] @ B[K,N]; tile 128x64, BK=32, 256 threads, 8x4 per thread.
// Per-output-element accumulation is a strictly ascending-k fused-fma chain
// with a single accumulator (canonical BLAS microkernel rounding).
// EPI=0: out0 = raw acc for cols<384 (qk), out1 = raw acc for cols>=384 (v).
// EPI=1: out0 = acc + bias.

#define BM 128
#define BN 64
#define BK 32

template <int EPI>
__global__ __launch_bounds__(256) void gemm_f32(const float* __restrict__ A,
                                                const float* __restrict__ Bm,
                                                const float* __restrict__ bias,
                                                float* __restrict__ out0,
                                                float* __restrict__ out1,
                                                int N, int K)
{
    __shared__ float As[BK][BM + 4];
    __shared__ float Bs[BK][BN];
    const int t    = threadIdx.x;
    const int row0 = blockIdx.x * BM;
    const int col0 = blockIdx.y * BN;
    const int tm   = t >> 4;   // 0..15 -> m offset tm*8
    const int tn   = t & 15;   // 0..15 -> n offset tn*4

    float acc[8][4];
    #pragma unroll
    for (int i = 0; i < 8; ++i)
        #pragma unroll
        for (int j = 0; j < 4; ++j) acc[i][j] = 0.f;

    const float* Ab = A + (size_t)row0 * K;

    for (int k0 = 0; k0 < K; k0 += BK) {
        __syncthreads();
        #pragma unroll
        for (int it = 0; it < 4; ++it) {
            int idx = it * 256 + t;
            int ar = idx >> 3, aq = idx & 7;
            float4 va = *(const float4*)(Ab + (size_t)ar * K + k0 + aq * 4);
            As[aq * 4 + 0][ar] = va.x;
            As[aq * 4 + 1][ar] = va.y;
            As[aq * 4 + 2][ar] = va.z;
            As[aq * 4 + 3][ar] = va.w;
        }
        #pragma unroll
        for (int it = 0; it < 2; ++it) {
            int idx = it * 256 + t;
            int br = idx >> 4, bq = idx & 15;
            *(float4*)&Bs[br][bq * 4] =
                *(const float4*)(Bm + (size_t)(k0 + br) * N + col0 + bq * 4);
        }
        __syncthreads();
        #pragma unroll
        for (int k = 0; k < BK; ++k) {
            float a[8], b[4];
            #pragma unroll
            for (int i = 0; i < 8; ++i) a[i] = As[k][tm * 8 + i];
            #pragma unroll
            for (int j = 0; j < 4; ++j) b[j] = Bs[k][tn * 4 + j];
            #pragma unroll
            for (int i = 0; i < 8; ++i)
                #pragma unroll
                for (int j = 0; j < 4; ++j)
                    acc[i][j] = fmaf(a[i], b[j], acc[i][j]);
        }
    }

    if (EPI == 0) {
        const bool isc = (col0 < 384);           // block-uniform (BN divides 384)
        float* dst = isc ? out0 : out1;
        const int cc = (isc ? col0 : col0 - 384) + tn * 4;
        #pragma unroll
        for (int i = 0; i < 8; ++i) {
            int m = row0 + tm * 8 + i;
            float4 r;
            r.x = acc[i][0]; r.y = acc[i][1];
            r.z = acc[i][2]; r.w = acc[i][3];
            *(float4*)&dst[(size_t)m * 384 + cc] = r;
        }
    } else {
        float4 bb = *(const float4*)&bias[col0 + tn * 4];
        #pragma unroll
        for (int i = 0; i < 8; ++i) {
            int m = row0 + tm * 8 + i;
            float4 r;
            r.x = acc[i][0] + bb.x; r.y = acc[i][1] + bb.y;
            r.z = acc[i][2] + bb.z; r.w = acc[i][3] + bb.w;
            *(float4*)&out0[(size_t)m * 384 + col0 + tn * 4] = r;
        }
    }
}

// ---------------- codes: f32 sign path (in place on qk) ----------------
// nrm: numpy pairwise 8-accumulator reduce of q*q (unfused mul/add), tree
//      combine ((r0+r1)+(r2+r3))+((r4+r5)+(r6+r7)), IEEE sqrt.
// qh = q / nrm (IEEE divide, per element).
// z[f]: single-accumulator ascending-d FUSED-FMA chain (canonical BLAS
//       microkernel order — OpenBLAS/Eigen/rocBLAS all reduce this way).
// code = sign(z).
__global__ __launch_bounds__(64) void codes_emu(float* __restrict__ zc,
                                                const float* __restrict__ hashp)
{
#pragma clang fp contract(off)
    const int bid  = blockIdx.x;          // < 262144
    const int row  = bid >> 3;            // global token (b*N + n)
    const int h    = bid & 7;
    const int lane = threadIdx.x;

    __shared__ float q[48];
    __shared__ float qh[48];
    __shared__ float nrm_s;

    float* base = zc + (size_t)row * 384 + h * 48;
    if (lane < 48) q[lane] = base[lane];
    __syncthreads();

    if (lane == 0) {
        float r[8];
        #pragma unroll
        for (int j = 0; j < 8; ++j) r[j] = q[j] * q[j];
        #pragma unroll
        for (int i = 8; i < 48; i += 8)
            #pragma unroll
            for (int j = 0; j < 8; ++j) r[j] = r[j] + q[i + j] * q[i + j];
        float s = ((r[0] + r[1]) + (r[2] + r[3])) + ((r[4] + r[5]) + (r[6] + r[7]));
        nrm_s = sqrtf(s);
    }
    __syncthreads();
    if (lane < 48) qh[lane] = q[lane] / nrm_s;
    __syncthreads();

    if (lane < 48) {
        const float* hp = hashp + (size_t)h * 2304 + (size_t)lane * 48;
        float z = 0.f;
        #pragma unroll
        for (int i = 0; i < 48; ++i)
            z = fmaf(qh[i], hp[i], z);   // ascending-d fused-fma chain
        base[lane] = z > 0.f ? 1.f : (z < 0.f ? -1.f : 0.f);
    }
}

// ---------------- attn = codes^T v  (per b,h: [48x4096]x[4096x48]) ----------------
__global__ __launch_bounds__(256) void attn_k(const float* __restrict__ codes,
                                              const float* __restrict__ v,
                                              float* __restrict__ attn)
{
    const int bh = blockIdx.x;
    const int b = bh >> 3, h = bh & 7;
    const int n0 = blockIdx.y * 512;
    __shared__ float cs[128][48];
    __shared__ float vs[128][48];
    const int t = threadIdx.x;
    const int fi = (t >> 4) * 3;
    const int di = (t & 15) * 3;
    float acc[3][3];
    #pragma unroll
    for (int i = 0; i < 3; ++i)
        #pragma unroll
        for (int j = 0; j < 3; ++j) acc[i][j] = 0.f;

    const size_t base = ((size_t)b * N_) * C_ + h * 48;
    for (int c0 = 0; c0 < 512; c0 += 128) {
        __syncthreads();
        #pragma unroll
        for (int l = 0; l < 6; ++l) {
            int idx = l * 256 + t;       // 0..1535
            int r = idx / 12, q = idx % 12;
            size_t g = base + (size_t)(n0 + c0 + r) * C_ + q * 4;
            *(float4*)&cs[r][q * 4] = *(const float4*)(codes + g);
            *(float4*)&vs[r][q * 4] = *(const float4*)(v + g);
        }
        __syncthreads();
        for (int nn = 0; nn < 128; ++nn) {
            float c0r = cs[nn][fi + 0], c1r = cs[nn][fi + 1], c2r = cs[nn][fi + 2];
            float v0 = vs[nn][di + 0], v1 = vs[nn][di + 1], v2 = vs[nn][di + 2];
            acc[0][0] = fmaf(c0r, v0, acc[0][0]);
            acc[0][1] = fmaf(c0r, v1, acc[0][1]);
            acc[0][2] = fmaf(c0r, v2, acc[0][2]);
            acc[1][0] = fmaf(c1r, v0, acc[1][0]);
            acc[1][1] = fmaf(c1r, v1, acc[1][1]);
            acc[1][2] = fmaf(c1r, v2, acc[1][2]);
            acc[2][0] = fmaf(c2r, v0, acc[2][0]);
            acc[2][1] = fmaf(c2r, v1, acc[2][1]);
            acc[2][2] = fmaf(c2r, v2, acc[2][2]);
        }
    }
    float* dst = attn + (size_t)bh * 2304;
    #pragma unroll
    for (int i = 0; i < 3; ++i)
        #pragma unroll
        for (int j = 0; j < 3; ++j)
            atomicAdd(&dst[(fi + i) * 48 + (di + j)], acc[i][j]);
}

// ---------------- out kernel: 0.5v + codes@attn/(48pi), normalize, + dconv ----------------
__device__ __forceinline__ void fma_row(float c, const float* __restrict__ ar,
                                        float4* __restrict__ s4)
{
    #pragma unroll
    for (int q = 0; q < 12; ++q) {
        float4 a = *(const float4*)(ar + q * 4);
        s4[q].x = fmaf(c, a.x, s4[q].x);
        s4[q].y = fmaf(c, a.y, s4[q].y);
        s4[q].z = fmaf(c, a.z, s4[q].z);
        s4[q].w = fmaf(c, a.w, s4[q].w);
    }
}

__global__ __launch_bounds__(256) void out_k(const float* __restrict__ codes,
                                             const float* __restrict__ v,
                                             const float* __restrict__ attn,
                                             const float* __restrict__ wd,
                                             float* __restrict__ y)
{
    const int bh = blockIdx.x;           // 64
    const int b = bh >> 3, h = bh & 7;
    const int t = threadIdx.x;
    const int n = blockIdx.y * 256 + t;  // token index
    __shared__ float As[48][48];
    {
        const float* ap = attn + (size_t)bh * 2304;
        const float SC = 1.0f / (48.0f * 3.14159265358979323846f);
        #pragma unroll
        for (int l = 0; l < 9; ++l) {
            int idx = l * 256 + t;
            As[idx / 48][idx % 48] = ap[idx] * SC;
        }
    }
    float wdl[9];
    #pragma unroll
    for (int k = 0; k < 9; ++k) wdl[k] = wd[h * 9 + k];
    __syncthreads();

    const size_t rowbase = ((size_t)(b * N_ + n)) * C_ + h * 48;

    float4 s4[12];
    #pragma unroll
    for (int q = 0; q < 12; ++q) s4[q] = make_float4(0.f, 0.f, 0.f, 0.f);
    for (int fq = 0; fq < 12; ++fq) {
        float4 cf = *(const float4*)(codes + rowbase + fq * 4);
        const float* a0 = &As[fq * 4][0];
        fma_row(cf.x, a0,        s4);
        fma_row(cf.y, a0 + 48,   s4);
        fma_row(cf.z, a0 + 96,   s4);
        fma_row(cf.w, a0 + 144,  s4);
    }

    float4 o4[12];
    float nrm = 0.f;
    {
        const float* vr = v + rowbase;
        #pragma unroll
        for (int q = 0; q < 12; ++q) {
            float4 vv = *(const float4*)(vr + q * 4);
            o4[q].x = fmaf(0.5f, vv.x, s4[q].x);
            o4[q].y = fmaf(0.5f, vv.y, s4[q].y);
            o4[q].z = fmaf(0.5f, vv.z, s4[q].z);
            o4[q].w = fmaf(0.5f, vv.w, s4[q].w);
            nrm = fmaf(o4[q].x, o4[q].x, nrm);
            nrm = fmaf(o4[q].y, o4[q].y, nrm);
            nrm = fmaf(o4[q].z, o4[q].z, nrm);
            nrm = fmaf(o4[q].w, o4[q].w, nrm);
        }
    }
    const float rn = 1.0f / sqrtf(nrm);

    float4 dc4[12];
    #pragma unroll
    for (int q = 0; q < 12; ++q) dc4[q] = make_float4(0.f, 0.f, 0.f, 0.f);
    for (int k = 0; k < 9; ++k) {
        int nn = n + k - 4;
        if ((unsigned)nn < (unsigned)N_) {
            const float* vr = v + ((size_t)(b * N_ + nn)) * C_ + h * 48;
            float wk = wdl[k];
            #pragma unroll
            for (int q = 0; q < 12; ++q) {
                float4 vv = *(const float4*)(vr + q * 4);
                dc4[q].x = fmaf(wk, vv.x, dc4[q].x);
                dc4[q].y = fmaf(wk, vv.y, dc4[q].y);
                dc4[q].z = fmaf(wk, vv.z, dc4[q].z);
                dc4[q].w = fmaf(wk, vv.w, dc4[q].w);
            }
        }
    }

    float* yr = y + rowbase;
    #pragma unroll
    for (int q = 0; q < 12; ++q) {
        float4 r;
        r.x = fmaf(o4[q].x, rn, dc4[q].x);
        r.y = fmaf(o4[q].y, rn, dc4[q].y);
        r.z = fmaf(o4[q].z, rn, dc4[q].z);
        r.w = fmaf(o4[q].w, rn, dc4[q].w);
        *(float4*)&yr[q * 4] = r;
    }
}

// ---------------- launch ----------------
extern "C" void kernel_launch(void* const* d_in, const int* in_sizes, int n_in,
                              void* d_out, int out_size, void* d_ws, size_t ws_size,
                              hipStream_t stream)
{
    const float* x      = (const float*)d_in[0];
    const float* w_qk   = (const float*)d_in[1];
    const float* w_v    = (const float*)d_in[2];
    const float* w_proj = (const float*)d_in[3];
    const float* b_proj = (const float*)d_in[4];
    const float* hashp  = (const float*)d_in[5];
    const float* wd     = (const float*)d_in[6];
    float* out = (float*)d_out;

    float* ws    = (float*)d_ws;
    float* W1    = ws;                        // 294912 f
    float* W3    = W1 + 294912;               // 147456 f
    float* zc    = W3 + 147456;               // 12582912 f (qk raw, then codes in place)
    float* vbuf  = zc + 12582912;             // 12582912 f
    float* attn  = vbuf + 12582912;           // 147456 f
    float* y     = attn + 147456;             // 12582912 f
    // total ~153 MB workspace

    hipLaunchKernelGGL(prep_w1, dim3(1152), dim3(256), 0, stream, w_qk, w_v, W1);
    hipLaunchKernelGGL(prep_w3, dim3(576), dim3(256), 0, stream, w_proj, W3);
    hipLaunchKernelGGL(zerok, dim3(576), dim3(256), 0, stream, attn, 147456);

    // [32768,384] @ [384,768] -> qk (raw) | v   (ascending-fmaf chains)
    hipLaunchKernelGGL((gemm_f32<0>), dim3(M_ / BM, 768 / BN), dim3(256), 0, stream,
                       x, W1, (const float*)nullptr, zc, vbuf, 768, 384);

    // normalize (numpy pairwise-8 order), hash-dot (ascending fused-fma), sign
    hipLaunchKernelGGL(codes_emu, dim3(262144), dim3(64), 0, stream, zc, hashp);

    hipLaunchKernelGGL(attn_k, dim3(64, 8), dim3(256), 0, stream, zc, vbuf, attn);
    hipLaunchKernelGGL(out_k, dim3(64, 16), dim3(256), 0, stream, zc, vbuf, attn, wd, y);

    // out = y @ w_proj^T + bias
    hipLaunchKernelGGL((gemm_f32<1>), dim3(M_ / BM, 384 / BN), dim3(256), 0, stream,
                       y, W3, b_proj, out, (float*)nullptr, 384, 384);
}

// Round 6
// 712.020 us; speedup vs baseline: 1.0945x; 1.0945x over previous
//
#include <hip/hip_runtime.h>

// Problem constants (B=8, N=4096, C=384, heads=8, head_dim=48)
#define B_   8
#define N_   4096
#define C_   384
#define NH_  8
#define HD_  48
#define M_   (B_ * N_)   // 32768 rows

// ======== FROZEN: codes path must stay bit-identical (sign-exact vs np ref) ========
// qk GEMM: single-accumulator ascending-k fmaf chain per element.
// norm: pairwise 8-acc unfused, tree combine; qh = q/nrm; z: ascending fused-fma.

// ---------------- prep kernels ----------------

// W1[k][n]: n<384 -> w_qk transposed (w_qk[n,k]); n>=384 -> w_v transposed.
__global__ __launch_bounds__(256) void prep_w1(const float* __restrict__ w_qk,
                                               const float* __restrict__ w_v,
                                               float* __restrict__ W1)
{
    int idx = blockIdx.x * 256 + threadIdx.x;   // < 384*768
    int k = idx / 768, n = idx % 768;
    W1[idx] = (n < 384) ? w_qk[(size_t)n * 384 + k]
                        : w_v[(size_t)(n - 384) * 384 + k];
}

// W3[k][n] = w_proj[n][k]
__global__ __launch_bounds__(256) void prep_w3(const float* __restrict__ w_proj,
                                               float* __restrict__ W3)
{
    int idx = blockIdx.x * 256 + threadIdx.x;   // < 384*384
    int k = idx / 384, n = idx % 384;
    W3[idx] = w_proj[n * 384 + k];
}

__global__ __launch_bounds__(256) void zerok(float* __restrict__ p, int n)
{
    int i = blockIdx.x * 256 + threadIdx.x;
    if (i < n) p[i] = 0.f;
}

// ---------------- fp32 tiled GEMM v2 ----------------
// 128x128 tile, BK=32, 256 threads, 8x8 per thread.
// As[128][33] row-major: stores <=2-way (free), reads conflict-free.
// Bs[32][128]: float4 stores, reads as 2x float4 (cols tn*4 and tn*4+64, 2-way free).
// Accumulation: single ascending-k fmaf chain per output element (BLAS order).
// EPI=0: out0 = raw acc cols<384 (qk), out1 = raw acc cols>=384 (v). ldc=384.
// EPI=1: out0 = acc + bias. ldc=384.

#define BM 128
#define BN 128
#define BK 32

template <int EPI>
__global__ __launch_bounds__(256, 4) void gemm_f32(const float* __restrict__ A,
                                                   const float* __restrict__ Bm,
                                                   const float* __restrict__ bias,
                                                   float* __restrict__ out0,
                                                   float* __restrict__ out1,
                                                   int N, int K)
{
    __shared__ float As[BM][BK + 1];   // [128][33]
    __shared__ float Bs[BK][BN];       // [32][128]
    const int t    = threadIdx.x;
    const int row0 = blockIdx.x * BM;
    const int col0 = blockIdx.y * BN;
    const int tm   = t >> 4;   // 0..15 -> rows tm*8..+7
    const int tn   = t & 15;   // 0..15 -> cols tn*4..+3 and tn*4+64..+67

    float acc[8][8];
    #pragma unroll
    for (int i = 0; i < 8; ++i)
        #pragma unroll
        for (int j = 0; j < 8; ++j) acc[i][j] = 0.f;

    const float* Ab = A + (size_t)row0 * K;

    for (int k0 = 0; k0 < K; k0 += BK) {
        __syncthreads();
        // stage A row-major: 128 rows x 32 k, 4 float4 loads / thread
        #pragma unroll
        for (int it = 0; it < 4; ++it) {
            int idx = it * 256 + t;            // 0..1023
            int ar = idx >> 3, aq = idx & 7;
            float4 va = *(const float4*)(Ab + (size_t)ar * K + k0 + aq * 4);
            As[ar][aq * 4 + 0] = va.x;
            As[ar][aq * 4 + 1] = va.y;
            As[ar][aq * 4 + 2] = va.z;
            As[ar][aq * 4 + 3] = va.w;
        }
        // stage B: 32 rows x 128 cols, 4 float4 / thread
        #pragma unroll
        for (int it = 0; it < 4; ++it) {
            int idx = it * 256 + t;            // 0..1023
            int br = idx >> 5, bq = idx & 31;
            *(float4*)&Bs[br][bq * 4] =
                *(const float4*)(Bm + (size_t)(k0 + br) * N + col0 + bq * 4);
        }
        __syncthreads();
        #pragma unroll
        for (int k = 0; k < BK; ++k) {
            float a[8], b[8];
            #pragma unroll
            for (int i = 0; i < 8; ++i) a[i] = As[tm * 8 + i][k];
            float4 b0 = *(const float4*)&Bs[k][tn * 4];
            float4 b1 = *(const float4*)&Bs[k][tn * 4 + 64];
            b[0] = b0.x; b[1] = b0.y; b[2] = b0.z; b[3] = b0.w;
            b[4] = b1.x; b[5] = b1.y; b[6] = b1.z; b[7] = b1.w;
            #pragma unroll
            for (int i = 0; i < 8; ++i)
                #pragma unroll
                for (int j = 0; j < 8; ++j)
                    acc[i][j] = fmaf(a[i], b[j], acc[i][j]);
        }
    }

    if (EPI == 0) {
        const bool isc = (col0 < 384);            // block-uniform (384 % BN-block = 0 per 128*3)
        float* dst = isc ? out0 : out1;
        const int cc = (isc ? col0 : col0 - 384) + tn * 4;
        #pragma unroll
        for (int i = 0; i < 8; ++i) {
            int m = row0 + tm * 8 + i;
            float4 r0, r1;
            r0.x = acc[i][0]; r0.y = acc[i][1]; r0.z = acc[i][2]; r0.w = acc[i][3];
            r1.x = acc[i][4]; r1.y = acc[i][5]; r1.z = acc[i][6]; r1.w = acc[i][7];
            *(float4*)&dst[(size_t)m * 384 + cc]      = r0;
            *(float4*)&dst[(size_t)m * 384 + cc + 64] = r1;
        }
    } else {
        float4 bb0 = *(const float4*)&bias[col0 + tn * 4];
        float4 bb1 = *(const float4*)&bias[col0 + tn * 4 + 64];
        #pragma unroll
        for (int i = 0; i < 8; ++i) {
            int m = row0 + tm * 8 + i;
            float4 r0, r1;
            r0.x = acc[i][0] + bb0.x; r0.y = acc[i][1] + bb0.y;
            r0.z = acc[i][2] + bb0.z; r0.w = acc[i][3] + bb0.w;
            r1.x = acc[i][4] + bb1.x; r1.y = acc[i][5] + bb1.y;
            r1.z = acc[i][6] + bb1.z; r1.w = acc[i][7] + bb1.w;
            *(float4*)&out0[(size_t)m * 384 + col0 + tn * 4]      = r0;
            *(float4*)&out0[(size_t)m * 384 + col0 + tn * 4 + 64] = r1;
        }
    }
}

// ---------------- codes: f32 sign path v2 (in place on qk) ----------------
// Per block: 16 rows x 1 head. hash[h] staged in LDS [48][49] (conflict-free).
// Bitwise-identical per-element math to v1:
//  - norm: pairwise 8-acc (unfused mul/add), tree combine, sqrtf (one thread/row)
//  - qh = q / nrm
//  - z[f]: single-accumulator ascending-d fused-fma chain; code = sign(z)
__global__ __launch_bounds__(256) void codes_emu(float* __restrict__ zc,
                                                 const float* __restrict__ hashp)
{
#pragma clang fp contract(off)
    const int h  = blockIdx.y;
    const int r0 = blockIdx.x * 16;
    const int t  = threadIdx.x;

    __shared__ float hs[48][49];
    __shared__ float qh[16][49];
    __shared__ float nrm_s[16];

    for (int idx = t; idx < 2304; idx += 256)
        hs[idx / 48][idx % 48] = hashp[(size_t)h * 2304 + idx];
    for (int idx = t; idx < 768; idx += 256) {
        int r = idx / 48, d = idx % 48;
        qh[r][d] = zc[(size_t)(r0 + r) * 384 + h * 48 + d];   // raw q for now
    }
    __syncthreads();

    if (t < 16) {
        float r[8];
        #pragma unroll
        for (int j = 0; j < 8; ++j) r[j] = qh[t][j] * qh[t][j];
        #pragma unroll
        for (int i = 8; i < 48; i += 8)
            #pragma unroll
            for (int j = 0; j < 8; ++j) r[j] = r[j] + qh[t][i + j] * qh[t][i + j];
        float s = ((r[0] + r[1]) + (r[2] + r[3])) + ((r[4] + r[5]) + (r[6] + r[7]));
        nrm_s[t] = sqrtf(s);
    }
    __syncthreads();

    for (int idx = t; idx < 768; idx += 256) {
        int r = idx / 48, d = idx % 48;
        qh[r][d] = qh[r][d] / nrm_s[r];
    }
    __syncthreads();

    const int r  = t >> 4;        // 0..15
    const int fg = t & 15;        // 0..15 -> f = fg*3 + j
    float* base = zc + (size_t)(r0 + r) * 384 + h * 48;
    #pragma unroll
    for (int j = 0; j < 3; ++j) {
        int f = fg * 3 + j;
        float z = 0.f;
        #pragma unroll
        for (int i = 0; i < 48; ++i)
            z = fmaf(qh[r][i], hs[f][i], z);   // ascending-d fused-fma chain
        base[f] = z > 0.f ? 1.f : (z < 0.f ? -1.f : 0.f);
    }
}

// ---------------- attn = codes^T v  (per b,h: [48x4096]x[4096x48]) ----------------
__global__ __launch_bounds__(256) void attn_k(const float* __restrict__ codes,
                                              const float* __restrict__ v,
                                              float* __restrict__ attn)
{
    const int bh = blockIdx.x;
    const int b = bh >> 3, h = bh & 7;
    const int n0 = blockIdx.y * 512;
    __shared__ float cs[128][48];
    __shared__ float vs[128][48];
    const int t = threadIdx.x;
    const int fi = (t >> 4) * 3;
    const int di = (t & 15) * 3;
    float acc[3][3];
    #pragma unroll
    for (int i = 0; i < 3; ++i)
        #pragma unroll
        for (int j = 0; j < 3; ++j) acc[i][j] = 0.f;

    const size_t base = ((size_t)b * N_) * C_ + h * 48;
    for (int c0 = 0; c0 < 512; c0 += 128) {
        __syncthreads();
        #pragma unroll
        for (int l = 0; l < 6; ++l) {
            int idx = l * 256 + t;       // 0..1535
            int r = idx / 12, q = idx % 12;
            size_t g = base + (size_t)(n0 + c0 + r) * C_ + q * 4;
            *(float4*)&cs[r][q * 4] = *(const float4*)(codes + g);
            *(float4*)&vs[r][q * 4] = *(const float4*)(v + g);
        }
        __syncthreads();
        for (int nn = 0; nn < 128; ++nn) {
            float c0r = cs[nn][fi + 0], c1r = cs[nn][fi + 1], c2r = cs[nn][fi + 2];
            float v0 = vs[nn][di + 0], v1 = vs[nn][di + 1], v2 = vs[nn][di + 2];
            acc[0][0] = fmaf(c0r, v0, acc[0][0]);
            acc[0][1] = fmaf(c0r, v1, acc[0][1]);
            acc[0][2] = fmaf(c0r, v2, acc[0][2]);
            acc[1][0] = fmaf(c1r, v0, acc[1][0]);
            acc[1][1] = fmaf(c1r, v1, acc[1][1]);
            acc[1][2] = fmaf(c1r, v2, acc[1][2]);
            acc[2][0] = fmaf(c2r, v0, acc[2][0]);
            acc[2][1] = fmaf(c2r, v1, acc[2][1]);
            acc[2][2] = fmaf(c2r, v2, acc[2][2]);
        }
    }
    float* dst = attn + (size_t)bh * 2304;
    #pragma unroll
    for (int i = 0; i < 3; ++i)
        #pragma unroll
        for (int j = 0; j < 3; ++j)
            atomicAdd(&dst[(fi + i) * 48 + (di + j)], acc[i][j]);
}

// ---------------- out kernel: 0.5v + codes@attn/(48pi), normalize, + dconv ----------------
__device__ __forceinline__ void fma_row(float c, const float* __restrict__ ar,
                                        float4* __restrict__ s4)
{
    #pragma unroll
    for (int q = 0; q < 12; ++q) {
        float4 a = *(const float4*)(ar + q * 4);
        s4[q].x = fmaf(c, a.x, s4[q].x);
        s4[q].y = fmaf(c, a.y, s4[q].y);
        s4[q].z = fmaf(c, a.z, s4[q].z);
        s4[q].w = fmaf(c, a.w, s4[q].w);
    }
}

__global__ __launch_bounds__(256) void out_k(const float* __restrict__ codes,
                                             const float* __restrict__ v,
                                             const float* __restrict__ attn,
                                             const float* __restrict__ wd,
                                             float* __restrict__ y)
{
    const int bh = blockIdx.x;           // 64
    const int b = bh >> 3, h = bh & 7;
    const int t = threadIdx.x;
    const int n = blockIdx.y * 256 + t;  // token index
    __shared__ float As[48][48];
    {
        const float* ap = attn + (size_t)bh * 2304;
        const float SC = 1.0f / (48.0f * 3.14159265358979323846f);
        #pragma unroll
        for (int l = 0; l < 9; ++l) {
            int idx = l * 256 + t;
            As[idx / 48][idx % 48] = ap[idx] * SC;
        }
    }
    float wdl[9];
    #pragma unroll
    for (int k = 0; k < 9; ++k) wdl[k] = wd[h * 9 + k];
    __syncthreads();

    const size_t rowbase = ((size_t)(b * N_ + n)) * C_ + h * 48;

    float4 s4[12];
    #pragma unroll
    for (int q = 0; q < 12; ++q) s4[q] = make_float4(0.f, 0.f, 0.f, 0.f);
    for (int fq = 0; fq < 12; ++fq) {
        float4 cf = *(const float4*)(codes + rowbase + fq * 4);
        const float* a0 = &As[fq * 4][0];
        fma_row(cf.x, a0,        s4);
        fma_row(cf.y, a0 + 48,   s4);
        fma_row(cf.z, a0 + 96,   s4);
        fma_row(cf.w, a0 + 144,  s4);
    }

    float4 o4[12];
    float nrm = 0.f;
    {
        const float* vr = v + rowbase;
        #pragma unroll
        for (int q = 0; q < 12; ++q) {
            float4 vv = *(const float4*)(vr + q * 4);
            o4[q].x = fmaf(0.5f, vv.x, s4[q].x);
            o4[q].y = fmaf(0.5f, vv.y, s4[q].y);
            o4[q].z = fmaf(0.5f, vv.z, s4[q].z);
            o4[q].w = fmaf(0.5f, vv.w, s4[q].w);
            nrm = fmaf(o4[q].x, o4[q].x, nrm);
            nrm = fmaf(o4[q].y, o4[q].y, nrm);
            nrm = fmaf(o4[q].z, o4[q].z, nrm);
            nrm = fmaf(o4[q].w, o4[q].w, nrm);
        }
    }
    const float rn = 1.0f / sqrtf(nrm);

    float4 dc4[12];
    #pragma unroll
    for (int q = 0; q < 12; ++q) dc4[q] = make_float4(0.f, 0.f, 0.f, 0.f);
    for (int k = 0; k < 9; ++k) {
        int nn = n + k - 4;
        if ((unsigned)nn < (unsigned)N_) {
            const float* vr = v + ((size_t)(b * N_ + nn)) * C_ + h * 48;
            float wk = wdl[k];
            #pragma unroll
            for (int q = 0; q < 12; ++q) {
                float4 vv = *(const float4*)(vr + q * 4);
                dc4[q].x = fmaf(wk, vv.x, dc4[q].x);
                dc4[q].y = fmaf(wk, vv.y, dc4[q].y);
                dc4[q].z = fmaf(wk, vv.z, dc4[q].z);
                dc4[q].w = fmaf(wk, vv.w, dc4[q].w);
            }
        }
    }

    float* yr = y + rowbase;
    #pragma unroll
    for (int q = 0; q < 12; ++q) {
        float4 r;
        r.x = fmaf(o4[q].x, rn, dc4[q].x);
        r.y = fmaf(o4[q].y, rn, dc4[q].y);
        r.z = fmaf(o4[q].z, rn, dc4[q].z);
        r.w = fmaf(o4[q].w, rn, dc4[q].w);
        *(float4*)&yr[q * 4] = r;
    }
}

// ---------------- launch ----------------
extern "C" void kernel_launch(void* const* d_in, const int* in_sizes, int n_in,
                              void* d_out, int out_size, void* d_ws, size_t ws_size,
                              hipStream_t stream)
{
    const float* x      = (const float*)d_in[0];
    const float* w_qk   = (const float*)d_in[1];
    const float* w_v    = (const float*)d_in[2];
    const float* w_proj = (const float*)d_in[3];
    const float* b_proj = (const float*)d_in[4];
    const float* hashp  = (const float*)d_in[5];
    const float* wd     = (const float*)d_in[6];
    float* out = (float*)d_out;

    float* ws    = (float*)d_ws;
    float* W1    = ws;                        // 294912 f
    float* W3    = W1 + 294912;               // 147456 f
    float* zc    = W3 + 147456;               // 12582912 f (qk raw, then codes in place)
    float* vbuf  = zc + 12582912;             // 12582912 f
    float* attn  = vbuf + 12582912;           // 147456 f
    float* y     = attn + 147456;             // 12582912 f
    // total ~153 MB workspace

    hipLaunchKernelGGL(prep_w1, dim3(1152), dim3(256), 0, stream, w_qk, w_v, W1);
    hipLaunchKernelGGL(prep_w3, dim3(576), dim3(256), 0, stream, w_proj, W3);
    hipLaunchKernelGGL(zerok, dim3(576), dim3(256), 0, stream, attn, 147456);

    // [32768,384] @ [384,768] -> qk (raw) | v   (ascending-fmaf chains)
    hipLaunchKernelGGL((gemm_f32<0>), dim3(M_ / BM, 768 / BN), dim3(256), 0, stream,
                       x, W1, (const float*)nullptr, zc, vbuf, 768, 384);

    // normalize (numpy pairwise-8 order), hash-dot (ascending fused-fma), sign
    hipLaunchKernelGGL(codes_emu, dim3(M_ / 16, 8), dim3(256), 0, stream, zc, hashp);

    hipLaunchKernelGGL(attn_k, dim3(64, 8), dim3(256), 0, stream, zc, vbuf, attn);
    hipLaunchKernelGGL(out_k, dim3(64, 16), dim3(256), 0, stream, zc, vbuf, attn, wd, y);

    // out = y @ w_proj^T + bias
    hipLaunchKernelGGL((gemm_f32<1>), dim3(M_ / BM, 384 / BN), dim3(256), 0, stream,
                       y, W3, b_proj, out, (float*)nullptr, 384, 384);
}

// Round 7
// 693.195 us; speedup vs baseline: 1.1243x; 1.0272x over previous
//
#include <hip/hip_runtime.h>

// Problem constants (B=8, N=4096, C=384, heads=8, head_dim=48)
#define B_   8
#define N_   4096
#define C_   384
#define NH_  8
#define HD_  48
#define M_   (B_ * N_)   // 32768 rows

// ======== FROZEN: codes path must stay bit-identical (sign-exact vs np ref) ========
// qk GEMM: single-accumulator ascending-k fmaf chain per element.
// norm: pairwise 8-acc unfused, tree combine; qh = q/nrm; z: ascending fused-fma.

// ---------------- prep kernels ----------------

// W1[k][n]: n<384 -> w_qk transposed (w_qk[n,k]); n>=384 -> w_v transposed.
__global__ __launch_bounds__(256) void prep_w1(const float* __restrict__ w_qk,
                                               const float* __restrict__ w_v,
                                               float* __restrict__ W1)
{
    int idx = blockIdx.x * 256 + threadIdx.x;   // < 384*768
    int k = idx / 768, n = idx % 768;
    W1[idx] = (n < 384) ? w_qk[(size_t)n * 384 + k]
                        : w_v[(size_t)(n - 384) * 384 + k];
}

// W3[k][n] = w_proj[n][k]
__global__ __launch_bounds__(256) void prep_w3(const float* __restrict__ w_proj,
                                               float* __restrict__ W3)
{
    int idx = blockIdx.x * 256 + threadIdx.x;   // < 384*384
    int k = idx / 384, n = idx % 384;
    W3[idx] = w_proj[n * 384 + k];
}

__global__ __launch_bounds__(256) void zerok(float* __restrict__ p, int n)
{
    int i = blockIdx.x * 256 + threadIdx.x;
    if (i < n) p[i] = 0.f;
}

// ---------------- fp32 tiled GEMM v3 ----------------
// 128x128 tile, BK=32, 256 threads, 8x8 per thread.
// launch_bounds(256,2): arch reg budget 256 -> acc[8][8]+a[8]+b[8] fully in
// registers, NO scratch spill (r6's (256,4) capped at 128 arch regs -> 210 MB
// of spill writes to HBM, VALUBusy wasted on spill code).
// As[128][33] row-major: stores <=2-way (free), reads broadcast (free).
// Bs[32][128]: float4 stores, reads 2x float4 (2-way, free).
// Accumulation: single ascending-k fmaf chain per output element (BLAS order).
// EPI=0: out0 = raw acc cols<384 (qk), out1 = raw acc cols>=384 (v). ldc=384.
// EPI=1: out0 = acc + bias. ldc=384.

#define BM 128
#define BN 128
#define BK 32

template <int EPI>
__global__ __launch_bounds__(256, 2) void gemm_f32(const float* __restrict__ A,
                                                   const float* __restrict__ Bm,
                                                   const float* __restrict__ bias,
                                                   float* __restrict__ out0,
                                                   float* __restrict__ out1,
                                                   int N, int K)
{
    __shared__ float As[BM][BK + 1];   // [128][33]
    __shared__ float Bs[BK][BN];       // [32][128]
    const int t    = threadIdx.x;
    const int row0 = blockIdx.x * BM;
    const int col0 = blockIdx.y * BN;
    const int tm   = t >> 4;   // 0..15 -> rows tm*8..+7
    const int tn   = t & 15;   // 0..15 -> cols tn*4..+3 and tn*4+64..+67

    float acc[8][8];
    #pragma unroll
    for (int i = 0; i < 8; ++i)
        #pragma unroll
        for (int j = 0; j < 8; ++j) acc[i][j] = 0.f;

    const float* Ab = A + (size_t)row0 * K;

    for (int k0 = 0; k0 < K; k0 += BK) {
        __syncthreads();
        // stage A row-major: 128 rows x 32 k, 4 float4 loads / thread
        #pragma unroll
        for (int it = 0; it < 4; ++it) {
            int idx = it * 256 + t;            // 0..1023
            int ar = idx >> 3, aq = idx & 7;
            float4 va = *(const float4*)(Ab + (size_t)ar * K + k0 + aq * 4);
            As[ar][aq * 4 + 0] = va.x;
            As[ar][aq * 4 + 1] = va.y;
            As[ar][aq * 4 + 2] = va.z;
            As[ar][aq * 4 + 3] = va.w;
        }
        // stage B: 32 rows x 128 cols, 4 float4 / thread
        #pragma unroll
        for (int it = 0; it < 4; ++it) {
            int idx = it * 256 + t;            // 0..1023
            int br = idx >> 5, bq = idx & 31;
            *(float4*)&Bs[br][bq * 4] =
                *(const float4*)(Bm + (size_t)(k0 + br) * N + col0 + bq * 4);
        }
        __syncthreads();
        #pragma unroll
        for (int k = 0; k < BK; ++k) {
            float a[8], b[8];
            #pragma unroll
            for (int i = 0; i < 8; ++i) a[i] = As[tm * 8 + i][k];
            float4 b0 = *(const float4*)&Bs[k][tn * 4];
            float4 b1 = *(const float4*)&Bs[k][tn * 4 + 64];
            b[0] = b0.x; b[1] = b0.y; b[2] = b0.z; b[3] = b0.w;
            b[4] = b1.x; b[5] = b1.y; b[6] = b1.z; b[7] = b1.w;
            #pragma unroll
            for (int i = 0; i < 8; ++i)
                #pragma unroll
                for (int j = 0; j < 8; ++j)
                    acc[i][j] = fmaf(a[i], b[j], acc[i][j]);
        }
    }

    if (EPI == 0) {
        const bool isc = (col0 < 384);            // block-uniform
        float* dst = isc ? out0 : out1;
        const int cc = (isc ? col0 : col0 - 384) + tn * 4;
        #pragma unroll
        for (int i = 0; i < 8; ++i) {
            int m = row0 + tm * 8 + i;
            float4 r0, r1;
            r0.x = acc[i][0]; r0.y = acc[i][1]; r0.z = acc[i][2]; r0.w = acc[i][3];
            r1.x = acc[i][4]; r1.y = acc[i][5]; r1.z = acc[i][6]; r1.w = acc[i][7];
            *(float4*)&dst[(size_t)m * 384 + cc]      = r0;
            *(float4*)&dst[(size_t)m * 384 + cc + 64] = r1;
        }
    } else {
        float4 bb0 = *(const float4*)&bias[col0 + tn * 4];
        float4 bb1 = *(const float4*)&bias[col0 + tn * 4 + 64];
        #pragma unroll
        for (int i = 0; i < 8; ++i) {
            int m = row0 + tm * 8 + i;
            float4 r0, r1;
            r0.x = acc[i][0] + bb0.x; r0.y = acc[i][1] + bb0.y;
            r0.z = acc[i][2] + bb0.z; r0.w = acc[i][3] + bb0.w;
            r1.x = acc[i][4] + bb1.x; r1.y = acc[i][5] + bb1.y;
            r1.z = acc[i][6] + bb1.z; r1.w = acc[i][7] + bb1.w;
            *(float4*)&out0[(size_t)m * 384 + col0 + tn * 4]      = r0;
            *(float4*)&out0[(size_t)m * 384 + col0 + tn * 4 + 64] = r1;
        }
    }
}

// ---------------- codes: f32 sign path v2 (in place on qk) ----------------
// Per block: 16 rows x 1 head. hash[h] staged in LDS [48][49] (conflict-free).
// Bitwise-identical per-element math to the r5-passing version:
//  - norm: pairwise 8-acc (unfused mul/add), tree combine, sqrtf (one thread/row)
//  - qh = q / nrm
//  - z[f]: single-accumulator ascending-d fused-fma chain; code = sign(z)
__global__ __launch_bounds__(256) void codes_emu(float* __restrict__ zc,
                                                 const float* __restrict__ hashp)
{
#pragma clang fp contract(off)
    const int h  = blockIdx.y;
    const int r0 = blockIdx.x * 16;
    const int t  = threadIdx.x;

    __shared__ float hs[48][49];
    __shared__ float qh[16][49];
    __shared__ float nrm_s[16];

    for (int idx = t; idx < 2304; idx += 256)
        hs[idx / 48][idx % 48] = hashp[(size_t)h * 2304 + idx];
    for (int idx = t; idx < 768; idx += 256) {
        int r = idx / 48, d = idx % 48;
        qh[r][d] = zc[(size_t)(r0 + r) * 384 + h * 48 + d];   // raw q for now
    }
    __syncthreads();

    if (t < 16) {
        float r[8];
        #pragma unroll
        for (int j = 0; j < 8; ++j) r[j] = qh[t][j] * qh[t][j];
        #pragma unroll
        for (int i = 8; i < 48; i += 8)
            #pragma unroll
            for (int j = 0; j < 8; ++j) r[j] = r[j] + qh[t][i + j] * qh[t][i + j];
        float s = ((r[0] + r[1]) + (r[2] + r[3])) + ((r[4] + r[5]) + (r[6] + r[7]));
        nrm_s[t] = sqrtf(s);
    }
    __syncthreads();

    for (int idx = t; idx < 768; idx += 256) {
        int r = idx / 48, d = idx % 48;
        qh[r][d] = qh[r][d] / nrm_s[r];
    }
    __syncthreads();

    const int r  = t >> 4;        // 0..15
    const int fg = t & 15;        // 0..15 -> f = fg*3 + j
    float* base = zc + (size_t)(r0 + r) * 384 + h * 48;
    #pragma unroll
    for (int j = 0; j < 3; ++j) {
        int f = fg * 3 + j;
        float z = 0.f;
        #pragma unroll
        for (int i = 0; i < 48; ++i)
            z = fmaf(qh[r][i], hs[f][i], z);   // ascending-d fused-fma chain
        base[f] = z > 0.f ? 1.f : (z < 0.f ? -1.f : 0.f);
    }
}

// ---------------- attn = codes^T v  (per b,h: [48x4096]x[4096x48]) ----------------
__global__ __launch_bounds__(256) void attn_k(const float* __restrict__ codes,
                                              const float* __restrict__ v,
                                              float* __restrict__ attn)
{
    const int bh = blockIdx.x;
    const int b = bh >> 3, h = bh & 7;
    const int n0 = blockIdx.y * 512;
    __shared__ float cs[128][48];
    __shared__ float vs[128][48];
    const int t = threadIdx.x;
    const int fi = (t >> 4) * 3;
    const int di = (t & 15) * 3;
    float acc[3][3];
    #pragma unroll
    for (int i = 0; i < 3; ++i)
        #pragma unroll
        for (int j = 0; j < 3; ++j) acc[i][j] = 0.f;

    const size_t base = ((size_t)b * N_) * C_ + h * 48;
    for (int c0 = 0; c0 < 512; c0 += 128) {
        __syncthreads();
        #pragma unroll
        for (int l = 0; l < 6; ++l) {
            int idx = l * 256 + t;       // 0..1535
            int r = idx / 12, q = idx % 12;
            size_t g = base + (size_t)(n0 + c0 + r) * C_ + q * 4;
            *(float4*)&cs[r][q * 4] = *(const float4*)(codes + g);
            *(float4*)&vs[r][q * 4] = *(const float4*)(v + g);
        }
        __syncthreads();
        for (int nn = 0; nn < 128; ++nn) {
            float c0r = cs[nn][fi + 0], c1r = cs[nn][fi + 1], c2r = cs[nn][fi + 2];
            float v0 = vs[nn][di + 0], v1 = vs[nn][di + 1], v2 = vs[nn][di + 2];
            acc[0][0] = fmaf(c0r, v0, acc[0][0]);
            acc[0][1] = fmaf(c0r, v1, acc[0][1]);
            acc[0][2] = fmaf(c0r, v2, acc[0][2]);
            acc[1][0] = fmaf(c1r, v0, acc[1][0]);
            acc[1][1] = fmaf(c1r, v1, acc[1][1]);
            acc[1][2] = fmaf(c1r, v2, acc[1][2]);
            acc[2][0] = fmaf(c2r, v0, acc[2][0]);
            acc[2][1] = fmaf(c2r, v1, acc[2][1]);
            acc[2][2] = fmaf(c2r, v2, acc[2][2]);
        }
    }
    float* dst = attn + (size_t)bh * 2304;
    #pragma unroll
    for (int i = 0; i < 3; ++i)
        #pragma unroll
        for (int j = 0; j < 3; ++j)
            atomicAdd(&dst[(fi + i) * 48 + (di + j)], acc[i][j]);
}

// ---------------- out kernel: 0.5v + codes@attn/(48pi), normalize, + dconv ----------------
__device__ __forceinline__ void fma_row(float c, const float* __restrict__ ar,
                                        float4* __restrict__ s4)
{
    #pragma unroll
    for (int q = 0; q < 12; ++q) {
        float4 a = *(const float4*)(ar + q * 4);
        s4[q].x = fmaf(c, a.x, s4[q].x);
        s4[q].y = fmaf(c, a.y, s4[q].y);
        s4[q].z = fmaf(c, a.z, s4[q].z);
        s4[q].w = fmaf(c, a.w, s4[q].w);
    }
}

__global__ __launch_bounds__(256) void out_k(const float* __restrict__ codes,
                                             const float* __restrict__ v,
                                             const float* __restrict__ attn,
                                             const float* __restrict__ wd,
                                             float* __restrict__ y)
{
    const int bh = blockIdx.x;           // 64
    const int b = bh >> 3, h = bh & 7;
    const int t = threadIdx.x;
    const int n = blockIdx.y * 256 + t;  // token index
    __shared__ float As[48][48];
    {
        const float* ap = attn + (size_t)bh * 2304;
        const float SC = 1.0f / (48.0f * 3.14159265358979323846f);
        #pragma unroll
        for (int l = 0; l < 9; ++l) {
            int idx = l * 256 + t;
            As[idx / 48][idx % 48] = ap[idx] * SC;
        }
    }
    float wdl[9];
    #pragma unroll
    for (int k = 0; k < 9; ++k) wdl[k] = wd[h * 9 + k];
    __syncthreads();

    const size_t rowbase = ((size_t)(b * N_ + n)) * C_ + h * 48;

    float4 s4[12];
    #pragma unroll
    for (int q = 0; q < 12; ++q) s4[q] = make_float4(0.f, 0.f, 0.f, 0.f);
    for (int fq = 0; fq < 12; ++fq) {
        float4 cf = *(const float4*)(codes + rowbase + fq * 4);
        const float* a0 = &As[fq * 4][0];
        fma_row(cf.x, a0,        s4);
        fma_row(cf.y, a0 + 48,   s4);
        fma_row(cf.z, a0 + 96,   s4);
        fma_row(cf.w, a0 + 144,  s4);
    }

    float4 o4[12];
    float nrm = 0.f;
    {
        const float* vr = v + rowbase;
        #pragma unroll
        for (int q = 0; q < 12; ++q) {
            float4 vv = *(const float4*)(vr + q * 4);
            o4[q].x = fmaf(0.5f, vv.x, s4[q].x);
            o4[q].y = fmaf(0.5f, vv.y, s4[q].y);
            o4[q].z = fmaf(0.5f, vv.z, s4[q].z);
            o4[q].w = fmaf(0.5f, vv.w, s4[q].w);
            nrm = fmaf(o4[q].x, o4[q].x, nrm);
            nrm = fmaf(o4[q].y, o4[q].y, nrm);
            nrm = fmaf(o4[q].z, o4[q].z, nrm);
            nrm = fmaf(o4[q].w, o4[q].w, nrm);
        }
    }
    const float rn = 1.0f / sqrtf(nrm);

    float4 dc4[12];
    #pragma unroll
    for (int q = 0; q < 12; ++q) dc4[q] = make_float4(0.f, 0.f, 0.f, 0.f);
    for (int k = 0; k < 9; ++k) {
        int nn = n + k - 4;
        if ((unsigned)nn < (unsigned)N_) {
            const float* vr = v + ((size_t)(b * N_ + nn)) * C_ + h * 48;
            float wk = wdl[k];
            #pragma unroll
            for (int q = 0; q < 12; ++q) {
                float4 vv = *(const float4*)(vr + q * 4);
                dc4[q].x = fmaf(wk, vv.x, dc4[q].x);
                dc4[q].y = fmaf(wk, vv.y, dc4[q].y);
                dc4[q].z = fmaf(wk, vv.z, dc4[q].z);
                dc4[q].w = fmaf(wk, vv.w, dc4[q].w);
            }
        }
    }

    float* yr = y + rowbase;
    #pragma unroll
    for (int q = 0; q < 12; ++q) {
        float4 r;
        r.x = fmaf(o4[q].x, rn, dc4[q].x);
        r.y = fmaf(o4[q].y, rn, dc4[q].y);
        r.z = fmaf(o4[q].z, rn, dc4[q].z);
        r.w = fmaf(o4[q].w, rn, dc4[q].w);
        *(float4*)&yr[q * 4] = r;
    }
}

// ---------------- launch ----------------
extern "C" void kernel_launch(void* const* d_in, const int* in_sizes, int n_in,
                              void* d_out, int out_size, void* d_ws, size_t ws_size,
                              hipStream_t stream)
{
    const float* x      = (const float*)d_in[0];
    const float* w_qk   = (const float*)d_in[1];
    const float* w_v    = (const float*)d_in[2];
    const float* w_proj = (const float*)d_in[3];
    const float* b_proj = (const float*)d_in[4];
    const float* hashp  = (const float*)d_in[5];
    const float* wd     = (const float*)d_in[6];
    float* out = (float*)d_out;

    float* ws    = (float*)d_ws;
    float* W1    = ws;                        // 294912 f
    float* W3    = W1 + 294912;               // 147456 f
    float* zc    = W3 + 147456;               // 12582912 f (qk raw, then codes in place)
    float* vbuf  = zc + 12582912;             // 12582912 f
    float* attn  = vbuf + 12582912;           // 147456 f
    float* y     = attn + 147456;             // 12582912 f
    // total ~153 MB workspace

    hipLaunchKernelGGL(prep_w1, dim3(1152), dim3(256), 0, stream, w_qk, w_v, W1);
    hipLaunchKernelGGL(prep_w3, dim3(576), dim3(256), 0, stream, w_proj, W3);
    hipLaunchKernelGGL(zerok, dim3(576), dim3(256), 0, stream, attn, 147456);

    // [32768,384] @ [384,768] -> qk (raw) | v   (ascending-fmaf chains)
    hipLaunchKernelGGL((gemm_f32<0>), dim3(M_ / BM, 768 / BN), dim3(256), 0, stream,
                       x, W1, (const float*)nullptr, zc, vbuf, 768, 384);

    // normalize (numpy pairwise-8 order), hash-dot (ascending fused-fma), sign
    hipLaunchKernelGGL(codes_emu, dim3(M_ / 16, 8), dim3(256), 0, stream, zc, hashp);

    hipLaunchKernelGGL(attn_k, dim3(64, 8), dim3(256), 0, stream, zc, vbuf, attn);
    hipLaunchKernelGGL(out_k, dim3(64, 16), dim3(256), 0, stream, zc, vbuf, attn, wd, y);

    // out = y @ w_proj^T + bias
    hipLaunchKernelGGL((gemm_f32<1>), dim3(M_ / BM, 384 / BN), dim3(256), 0, stream,
                       y, W3, b_proj, out, (float*)nullptr, 384, 384);
}